// Round 1
// baseline (1546.833 us; speedup 1.0000x reference)
//
#include <hip/hip_runtime.h>
#include <cstdint>

#define NOUTC 131072
#define NINC  16384

using uint = unsigned int;

__device__ __forceinline__ uint fkey(float v){
  uint u = __float_as_uint(v);
  return (u & 0x80000000u) ? ~u : (u | 0x80000000u);
}

// ---------------------------------------------------------------------------
// Generic sparse-conv gather-GEMM tile kernel.
// feats: [N+1, CIN] with row N == zeros (sentinel). nbr: [NK, N] (ignored if IDENT).
// W: [NK, CIN, COUT]. out[r, coff + c] (stride ostride), optional relu / residual add.
// ---------------------------------------------------------------------------
template<int ROWS, int CIN, int COUT, int TR, int TC, int NK, bool IDENT, bool RELU, bool RESID>
__global__ __launch_bounds__(256)
void spconv(const float* __restrict__ feats,
            const int*   __restrict__ nbr,
            const float* __restrict__ Wg,
            const float* __restrict__ bias,
            const float* __restrict__ resid,
            float*       __restrict__ outp,
            int ostride, int coff)
{
  static_assert(TR == 4, "TR must be 4");
  static_assert((ROWS / TR) * (COUT / TC) == 256, "thread tiling must cover 256 threads");
  constexpr int TPR = 256 / ROWS;            // threads per gathered row
  static_assert(ROWS * TPR == 256, "");
  constexpr int GV = CIN / (4 * TPR);        // float4 loads per thread in gather
  static_assert(CIN % (4 * TPR) == 0, "");
  constexpr int STR = ROWS + 4;

  __shared__ float Wl[CIN * COUT];
  __shared__ float ft[CIN][STR];

  const int t    = threadIdx.x;
  const int base = blockIdx.x * ROWS;

  constexpr int CT = COUT / TC;
  const int tcc = (t % CT) * TC;
  const int trr = (t / CT) * TR;

  const int gr    = t / TPR;
  const int gpart = t % TPR;

  float acc[TR][TC];
  #pragma unroll
  for (int a = 0; a < TR; ++a)
    #pragma unroll
    for (int b = 0; b < TC; ++b) acc[a][b] = 0.f;

  for (int k = 0; k < NK; ++k) {
    // stage W[k] into LDS (coalesced)
    #pragma unroll
    for (int i = t; i < CIN * COUT; i += 256) Wl[i] = Wg[k * CIN * COUT + i];
    // gather ROWS feature rows, write transposed
    int gidx = IDENT ? (base + gr) : nbr[(size_t)k * NOUTC + base + gr];
    const float4* src = reinterpret_cast<const float4*>(feats + (size_t)gidx * CIN) + gpart * GV;
    #pragma unroll
    for (int j = 0; j < GV; ++j) {
      float4 v = src[j];
      int ci = (gpart * GV + j) * 4;
      ft[ci + 0][gr] = v.x; ft[ci + 1][gr] = v.y;
      ft[ci + 2][gr] = v.z; ft[ci + 3][gr] = v.w;
    }
    __syncthreads();
    #pragma unroll
    for (int ci = 0; ci < CIN; ++ci) {
      float4 f = *reinterpret_cast<const float4*>(&ft[ci][trr]);
      float fv[4] = {f.x, f.y, f.z, f.w};
      float wv[TC];
      if constexpr (TC == 4) {
        float4 w = *reinterpret_cast<const float4*>(&Wl[ci * COUT + tcc]);
        wv[0] = w.x; wv[1] = w.y; wv[2] = w.z; wv[3] = w.w;
      } else {
        float2 w = *reinterpret_cast<const float2*>(&Wl[ci * COUT + tcc]);
        wv[0] = w.x; wv[1] = w.y;
      }
      #pragma unroll
      for (int a = 0; a < TR; ++a)
        #pragma unroll
        for (int b = 0; b < TC; ++b)
          acc[a][b] = fmaf(fv[a], wv[b], acc[a][b]);
    }
    __syncthreads();
  }

  // epilogue
  #pragma unroll
  for (int a = 0; a < TR; ++a) {
    int rr = base + trr + a;
    float o[TC];
    #pragma unroll
    for (int b = 0; b < TC; ++b) {
      float v = acc[a][b] + bias[tcc + b];
      if (RELU) v = v > 0.f ? v : 0.f;
      o[b] = v;
    }
    if (RESID) {
      #pragma unroll
      for (int b = 0; b < TC; ++b)
        o[b] += resid[(size_t)rr * 64 + coff + tcc + b];
    }
    float* dst = outp + (size_t)rr * ostride + coff + tcc;
    if constexpr (TC == 4) {
      float4 w4 = {o[0], o[1], o[2], o[3]};
      *reinterpret_cast<float4*>(dst) = w4;
    } else {
      float2 w2 = {o[0], o[1]};
      *reinterpret_cast<float2*>(dst) = w2;
    }
  }
}

// ---------------------------------------------------------------------------
// upsample: out[(n*8+k)*64 + c] = relu(x[n] @ Wup[k] + bup)
// block = (tile of 64 input rows, k); grid = 256*8
// ---------------------------------------------------------------------------
__global__ __launch_bounds__(256)
void upsample_kernel(const float* __restrict__ x, const float* __restrict__ Wup,
                     const float* __restrict__ bup, float* __restrict__ outp)
{
  __shared__ float Wl[64 * 64];
  __shared__ float xt[64][68];
  const int t    = threadIdx.x;
  const int tile = blockIdx.x >> 3;
  const int k    = blockIdx.x & 7;
  const int base = tile * 64;

  #pragma unroll
  for (int i = t; i < 4096; i += 256) Wl[i] = Wup[k * 4096 + i];
  {
    const int gr = t >> 2, gp = t & 3;
    const float4* src = reinterpret_cast<const float4*>(x + (size_t)(base + gr) * 64) + gp * 4;
    #pragma unroll
    for (int j = 0; j < 4; ++j) {
      float4 v = src[j];
      int ci = (gp * 4 + j) * 4;
      xt[ci + 0][gr] = v.x; xt[ci + 1][gr] = v.y;
      xt[ci + 2][gr] = v.z; xt[ci + 3][gr] = v.w;
    }
  }
  __syncthreads();
  const int tcc = (t % 16) * 4, trr = (t / 16) * 4;
  float acc[4][4];
  #pragma unroll
  for (int a = 0; a < 4; ++a)
    #pragma unroll
    for (int b = 0; b < 4; ++b) acc[a][b] = 0.f;
  #pragma unroll
  for (int ci = 0; ci < 64; ++ci) {
    float4 f = *reinterpret_cast<const float4*>(&xt[ci][trr]);
    float4 w = *reinterpret_cast<const float4*>(&Wl[ci * 64 + tcc]);
    float fv[4] = {f.x, f.y, f.z, f.w};
    float wv[4] = {w.x, w.y, w.z, w.w};
    #pragma unroll
    for (int a = 0; a < 4; ++a)
      #pragma unroll
      for (int b = 0; b < 4; ++b) acc[a][b] = fmaf(fv[a], wv[b], acc[a][b]);
  }
  #pragma unroll
  for (int a = 0; a < 4; ++a) {
    int n = base + trr + a;
    float4 o;
    float v0 = acc[a][0] + bup[tcc + 0]; o.x = v0 > 0.f ? v0 : 0.f;
    float v1 = acc[a][1] + bup[tcc + 1]; o.y = v1 > 0.f ? v1 : 0.f;
    float v2 = acc[a][2] + bup[tcc + 2]; o.z = v2 > 0.f ? v2 : 0.f;
    float v3 = acc[a][3] + bup[tcc + 3]; o.w = v3 > 0.f ? v3 : 0.f;
    *reinterpret_cast<float4*>(outp + ((size_t)n * 8 + k) * 64 + tcc) = o;
  }
}

// ---------------------------------------------------------------------------
// classifier conv: out_cls[n] = sum_k feats[nbr[k][n]] . Wcls[k][:,0] + bcls
// one wave per row group; lane = channel
// ---------------------------------------------------------------------------
__global__ __launch_bounds__(256)
void cls_kernel(const float* __restrict__ feats, const int* __restrict__ nbr,
                const float* __restrict__ Wcls, const float* __restrict__ bcls,
                float* __restrict__ out_cls)
{
  const int wave = threadIdx.x >> 6;
  const int lane = threadIdx.x & 63;
  float wreg[27];
  #pragma unroll
  for (int k = 0; k < 27; ++k) wreg[k] = Wcls[k * 64 + lane];
  const int base = blockIdx.x * 32 + wave * 8;
  for (int rr = 0; rr < 8; ++rr) {
    const int n = base + rr;
    float s = 0.f;
    #pragma unroll
    for (int k = 0; k < 27; ++k) {
      int idx = nbr[(size_t)k * NOUTC + n];
      s = fmaf(feats[(size_t)idx * 64 + lane], wreg[k], s);
    }
    #pragma unroll
    for (int off = 32; off >= 1; off >>= 1) s += __shfl_xor(s, off, 64);
    if (lane == 0) out_cls[n] = s + bcls[0];
  }
}

// ---------------------------------------------------------------------------
// init / detect / top-k select / prune
// ---------------------------------------------------------------------------
__global__ void init_kernel(uint* hist1, uint* hist2, int* tie_cnt, int* flag,
                            float* fa, float* fb, float* t0, float* t1)
{
  int i = blockIdx.x * 256 + threadIdx.x;
  if (i < 65536) hist1[i] = 0;
  else if (i < 131072) hist2[i - 65536] = 0;
  if (i == 0) { tie_cnt[0] = 0; flag[0] = 0; }
  if (i < 64) { fa[(size_t)NOUTC * 64 + i] = 0.f; fb[(size_t)NOUTC * 64 + i] = 0.f; }
  if (i < 16) { t0[(size_t)NOUTC * 16 + i] = 0.f; t1[(size_t)NOUTC * 16 + i] = 0.f; }
}

// detect whether mask_true is stored as 1-byte bools (flag=1) or 4-byte ints (flag=0)
__global__ void detect_kernel(const unsigned char* __restrict__ mt, int* flag)
{
  int i = blockIdx.x * 256 + threadIdx.x;  // i < NOUTC/4
  int p = i * 4 + 1;
  if (p < NOUTC && mt[p] != 0) flag[0] = 1;
}

__global__ void hist1_kernel(const float* __restrict__ cls, uint* __restrict__ hist)
{
  for (int i = blockIdx.x * blockDim.x + threadIdx.x; i < NOUTC; i += gridDim.x * blockDim.x)
    atomicAdd(&hist[fkey(cls[i]) >> 16], 1u);
}

__global__ void scan1_kernel(const uint* __restrict__ hist, const int* __restrict__ nums,
                             uint* __restrict__ res)
{
  __shared__ uint chunk[256];
  const int t = threadIdx.x;
  uint s = 0;
  for (int j = 0; j < 256; ++j) s += hist[t * 256 + j];
  chunk[t] = s;
  __syncthreads();
  if (t == 0) {
    uint k = (uint)nums[0];
    uint cum = 0; int c = 255;
    for (; c > 0; --c) { if (cum + chunk[c] >= k) break; cum += chunk[c]; }
    int B = c * 256; uint cum2 = cum;
    for (int b = c * 256 + 255; b >= c * 256; --b) {
      if (cum2 + hist[b] >= k) { B = b; break; }
      cum2 += hist[b];
    }
    res[0] = (uint)B; res[1] = cum2;
  }
}

__global__ void hist2_kernel(const float* __restrict__ cls, const uint* __restrict__ res1,
                             uint* __restrict__ hist)
{
  const uint B = res1[0];
  for (int i = blockIdx.x * blockDim.x + threadIdx.x; i < NOUTC; i += gridDim.x * blockDim.x) {
    uint key = fkey(cls[i]);
    if ((key >> 16) == B) atomicAdd(&hist[key & 0xffffu], 1u);
  }
}

__global__ void scan2_kernel(const uint* __restrict__ hist, const uint* __restrict__ res1,
                             const int* __restrict__ nums, uint* __restrict__ res2)
{
  __shared__ uint chunk[256];
  const int t = threadIdx.x;
  uint s = 0;
  for (int j = 0; j < 256; ++j) s += hist[t * 256 + j];
  chunk[t] = s;
  __syncthreads();
  if (t == 0) {
    uint k = (uint)nums[0];
    uint cum = res1[1]; int c = 255;
    for (; c > 0; --c) { if (cum + chunk[c] >= k) break; cum += chunk[c]; }
    int L = c * 256; uint cum2 = cum;
    for (int b = c * 256 + 255; b >= c * 256; --b) {
      if (cum2 + hist[b] >= k) { L = b; break; }
      cum2 += hist[b];
    }
    res2[0] = (res1[0] << 16) | (uint)L;  // threshold key T
    res2[1] = k - cum2;                    // how many ties (==T) to take
  }
}

__global__ void mark_kernel(const float* __restrict__ cls, const uint* __restrict__ res2,
                            unsigned char* __restrict__ msel, int* tie_cnt, int* tie_idx)
{
  const uint T = res2[0];
  for (int i = blockIdx.x * blockDim.x + threadIdx.x; i < NOUTC; i += gridDim.x * blockDim.x) {
    uint key = fkey(cls[i]);
    msel[i] = key > T ? 1 : 0;
    if (key == T) {
      int p = atomicAdd(tie_cnt, 1);
      if (p < 4096) tie_idx[p] = i;
    }
  }
}

// stable tie-break: among values == T, take smallest indices first (lax.top_k semantics)
__global__ void tie_kernel(const uint* __restrict__ res2, const int* __restrict__ tie_cnt,
                           const int* __restrict__ tie_idx, unsigned char* __restrict__ msel)
{
  int need = (int)res2[1];
  int cnt = tie_cnt[0]; if (cnt > 4096) cnt = 4096;
  if (need <= 0) return;
  if (cnt <= need) {
    for (int i = threadIdx.x; i < cnt; i += 256) msel[tie_idx[i]] = 1;
  } else {
    for (int i = threadIdx.x; i < cnt; i += 256) {
      int my = tie_idx[i];
      int rank = 0;
      for (int j = 0; j < cnt; ++j) rank += (tie_idx[j] < my) ? 1 : 0;
      if (rank < need) msel[my] = 1;
    }
  }
}

__global__ void prune_kernel(const float* __restrict__ feats, const unsigned char* __restrict__ msel,
                             const void* __restrict__ mtrue, const int* __restrict__ flag,
                             float* __restrict__ dout)
{
  const unsigned char* mb = (const unsigned char*)mtrue;
  const int* mi = (const int*)mtrue;
  const bool bytes = (flag[0] != 0);
  float* pruned = dout + NOUTC;
  float* maskf  = dout + NOUTC + (size_t)NOUTC * 64;
  const float4* src = reinterpret_cast<const float4*>(feats);
  float4* dst = reinterpret_cast<float4*>(pruned);
  const int total = NOUTC * 16;
  for (int i = blockIdx.x * blockDim.x + threadIdx.x; i < total; i += gridDim.x * blockDim.x) {
    int n = i >> 4;
    bool mt = bytes ? (mb[n] != 0) : (mi[n] != 0);
    bool m = (msel[n] != 0) || mt;
    float4 v = src[i];
    float4 z = {0.f, 0.f, 0.f, 0.f};
    dst[i] = m ? v : z;
    if ((i & 15) == 0) maskf[n] = m ? 1.f : 0.f;
  }
}

// ---------------------------------------------------------------------------
extern "C" void kernel_launch(void* const* d_in, const int* in_sizes, int n_in,
                              void* d_out, int out_size, void* d_ws, size_t ws_size,
                              hipStream_t stream)
{
  const float* x    = (const float*)d_in[0];
  const float* Wup  = (const float*)d_in[1];
  const float* bup  = (const float*)d_in[2];
  const float* Wc0  = (const float*)d_in[3];
  const float* bc0  = (const float*)d_in[4];
  const float* W00  = (const float*)d_in[5];
  const float* b00  = (const float*)d_in[6];
  const float* W01  = (const float*)d_in[7];
  const float* b01  = (const float*)d_in[8];
  const float* W10  = (const float*)d_in[9];
  const float* b10  = (const float*)d_in[10];
  const float* W11  = (const float*)d_in[11];
  const float* b11  = (const float*)d_in[12];
  const float* W12  = (const float*)d_in[13];
  const float* b12  = (const float*)d_in[14];
  const float* Wcls = (const float*)d_in[15];
  const float* bcls = (const float*)d_in[16];
  const int*   nbr  = (const int*)d_in[17];
  const void*  mtrue= d_in[18];
  const int*   nums = (const int*)d_in[19];

  float* dout = (float*)d_out;

  // workspace layout (floats)
  float* fa = (float*)d_ws;                         // (N+1)*64
  float* t0 = fa + (size_t)(NOUTC + 1) * 64;        // (N+1)*16
  float* t1 = t0 + (size_t)(NOUTC + 1) * 16;        // (N+1)*16
  uint*  hist1 = (uint*)(t1 + (size_t)(NOUTC + 1) * 16);
  uint*  hist2 = hist1 + 65536;
  uint*  res1  = hist2 + 65536;   // [B, count_above]
  uint*  res2  = res1 + 2;        // [T, need]
  int*   tie_cnt = (int*)(res2 + 2);
  int*   flag    = tie_cnt + 1;
  int*   tie_idx = flag + 1;      // 4096
  unsigned char* msel = (unsigned char*)(tie_idx + 4096);  // NOUTC bytes
  // feat_b lives in d_out's pruned region (dead before prune writes it)
  float* fb = dout + NOUTC;       // (N+1)*64 fits: N + N*64 + 64 <= N*66

  init_kernel<<<512, 256, 0, stream>>>(hist1, hist2, tie_cnt, flag, fa, fb, t0, t1);
  detect_kernel<<<128, 256, 0, stream>>>((const unsigned char*)mtrue, flag);

  // up = relu(einsum + bup) -> fa
  upsample_kernel<<<2048, 256, 0, stream>>>(x, Wup, bup, fa);
  // out = relu(spconv(fa, Wc0)) -> fb
  spconv<64, 64, 64, 4, 4, 27, false, true, false>
      <<<NOUTC / 64, 256, 0, stream>>>(fa, nbr, Wc0, bc0, nullptr, fb, 64, 0);

  const float* cur = fb; float* nxt = fa;
  for (int i = 0; i < 3; ++i) {
    // t0 = relu(spconv(cur, W00))
    spconv<128, 64, 16, 4, 2, 27, false, true, false>
        <<<NOUTC / 128, 256, 0, stream>>>(cur, nbr, W00 + (size_t)i * 27 * 64 * 16,
                                          b00 + i * 16, nullptr, t0, 16, 0);
    // nxt[:,0:32] = spconv(t0, W01) + b01 + cur[:,0:32]
    spconv<128, 16, 32, 4, 4, 27, false, false, true>
        <<<NOUTC / 128, 256, 0, stream>>>(t0, nbr, W01 + (size_t)i * 27 * 16 * 32,
                                          b01 + i * 32, cur, nxt, 64, 0);
    // t1 = relu(cur @ W10 + b10)
    spconv<128, 64, 16, 4, 2, 1, true, true, false>
        <<<NOUTC / 128, 256, 0, stream>>>(cur, nullptr, W10 + (size_t)i * 64 * 16,
                                          b10 + i * 16, nullptr, t1, 16, 0);
    // t2 = relu(spconv(t1, W11)) -> reuse t0 buffer
    spconv<128, 16, 16, 4, 2, 27, false, true, false>
        <<<NOUTC / 128, 256, 0, stream>>>(t1, nbr, W11 + (size_t)i * 27 * 16 * 16,
                                          b11 + i * 16, nullptr, t0, 16, 0);
    // nxt[:,32:64] = t2 @ W12 + b12 + cur[:,32:64]
    spconv<128, 16, 32, 4, 4, 1, true, false, true>
        <<<NOUTC / 128, 256, 0, stream>>>(t0, nullptr, W12 + (size_t)i * 16 * 32,
                                          b12 + i * 32, cur, nxt, 64, 32);
    float* tmp = (float*)cur; cur = nxt; nxt = tmp;
  }
  // after 3 blocks, final features are in `cur` (== fa)

  cls_kernel<<<NOUTC / 32, 256, 0, stream>>>(cur, nbr, Wcls, bcls, dout);

  hist1_kernel<<<512, 256, 0, stream>>>(dout, hist1);
  scan1_kernel<<<1, 256, 0, stream>>>(hist1, nums, res1);
  hist2_kernel<<<512, 256, 0, stream>>>(dout, res1, hist2);
  scan2_kernel<<<1, 256, 0, stream>>>(hist2, res1, nums, res2);
  mark_kernel<<<512, 256, 0, stream>>>(dout, res2, msel, tie_cnt, tie_idx);
  tie_kernel<<<1, 256, 0, stream>>>(res2, tie_cnt, tie_idx, msel);
  prune_kernel<<<4096, 256, 0, stream>>>(cur, msel, mtrue, flag, dout);
}

// Round 2
// 1297.142 us; speedup vs baseline: 1.1925x; 1.1925x over previous
//
#include <hip/hip_runtime.h>
#include <cstdint>

#define NOUTC 131072
#define NINC  16384

using uint = unsigned int;

__device__ __forceinline__ uint fkey(float v){
  uint u = __float_as_uint(v);
  return (u & 0x80000000u) ? ~u : (u | 0x80000000u);
}

// ---------------------------------------------------------------------------
// Sparse-conv gather-GEMM, 8x8 register tiles, ci-split, reg-prefetch pipeline.
// feats: [N+1, CIN] row N zeros. nbr: [NK, N]. W: [NK, CIN, COUT].
// Thread map (sp-fastest): sp = t%SPLIT, slot = t/SPLIT, rg = slot/CG, cg = slot%CG.
// ci partition strided: ci = sp + SPLIT*i  (bank-spreads sp into LDS reads).
// ---------------------------------------------------------------------------
template<int ROWS, int CIN, int COUT, int SPLIT, int THREADS, int NK,
         bool IDENT, bool RELU, bool RESID>
__global__ __launch_bounds__(THREADS)
void spconv2(const float* __restrict__ feats, const int* __restrict__ nbr,
             const float* __restrict__ Wg, const float* __restrict__ bias,
             const float* __restrict__ resid, float* __restrict__ outp,
             int ostride, int coff)
{
  constexpr int RG = ROWS / 8, CG = COUT / 8;
  static_assert(RG * CG * SPLIT == THREADS, "bad thread tiling");
  constexpr int CIPT = CIN / SPLIT;
  static_assert(CIPT * SPLIT == CIN, "");
  constexpr int STR  = ROWS + 4;              // ft stride: 16B-aligned, ==4 mod 32
  constexpr int WSTR = COUT + 4;              // Wl stride: 16B-aligned, ==4 mod 32
  constexpr int TPR  = THREADS / ROWS;        // threads cooperating on one row
  static_assert(TPR * ROWS == THREADS, "");
  constexpr int FSTG = CIN / TPR;             // floats gathered per thread
  static_assert(FSTG % 4 == 0, "");
  constexpr int WSTG = (CIN * COUT) / THREADS;
  constexpr int NSLOT = THREADS / SPLIT;

  constexpr int MAIN_FL = CIN * STR + CIN * WSTR;
  constexpr int RED_FL  = (SPLIT > 1) ? (THREADS / 2) * 64 : 0;
  constexpr int LDS_FL  = MAIN_FL > RED_FL ? MAIN_FL : RED_FL;
  __shared__ float smem[LDS_FL];
  float* ft = smem;                 // [CIN][STR] transposed features
  float* Wl = smem + CIN * STR;     // [CIN][WSTR]

  const int t    = threadIdx.x;
  const int base = blockIdx.x * ROWS;
  const int sp   = t % SPLIT;
  const int slot = t / SPLIT;
  const int rg = slot / CG, cg = slot % CG;
  const int trr = rg * 8, tcc = cg * 8;
  const int gr = t / TPR, part = t % TPR;

  float4 fstg[FSTG / 4];
  alignas(16) float wstg[WSTG];
  float acc[8][8];
  #pragma unroll
  for (int a = 0; a < 8; ++a)
    #pragma unroll
    for (int b = 0; b < 8; ++b) acc[a][b] = 0.f;

  auto load_f = [&](int k) {
    int gidx = IDENT ? (base + gr) : nbr[(size_t)k * NOUTC + base + gr];
    const float4* src = reinterpret_cast<const float4*>(feats + (size_t)gidx * CIN + part * FSTG);
    #pragma unroll
    for (int j = 0; j < FSTG / 4; ++j) fstg[j] = src[j];
  };
  auto load_w = [&](int k) {
    const float* wsrc = Wg + (size_t)k * CIN * COUT + t * WSTG;
    if constexpr (WSTG % 4 == 0) {
      #pragma unroll
      for (int m = 0; m < WSTG / 4; ++m)
        *reinterpret_cast<float4*>(&wstg[4 * m]) = reinterpret_cast<const float4*>(wsrc)[m];
    } else {
      *reinterpret_cast<float2*>(&wstg[0]) = *reinterpret_cast<const float2*>(wsrc);
    }
  };

  load_f(0); load_w(0);

  for (int k = 0; k < NK; ++k) {
    // ---- write staged regs to LDS (waits the loads issued a phase ago) ----
    #pragma unroll
    for (int j = 0; j < FSTG / 4; ++j) {
      int ci = part * FSTG + 4 * j;
      ft[(ci + 0) * STR + gr] = fstg[j].x;
      ft[(ci + 1) * STR + gr] = fstg[j].y;
      ft[(ci + 2) * STR + gr] = fstg[j].z;
      ft[(ci + 3) * STR + gr] = fstg[j].w;
    }
    #pragma unroll
    for (int m = 0; m < WSTG; ++m) {
      int widx = t * WSTG + m;
      Wl[(widx / COUT) * WSTR + (widx % COUT)] = wstg[m];
    }
    __syncthreads();
    // ---- issue next-k global loads; they fly under the compute below ----
    if (k + 1 < NK) { load_f(k + 1); load_w(k + 1); }
    // ---- compute: 8x8 outer product per thread over this thread's ci set ----
    #pragma unroll 4
    for (int i = 0; i < CIPT; ++i) {
      int ci = sp + SPLIT * i;
      float4 f0 = *reinterpret_cast<const float4*>(&ft[ci * STR + trr]);
      float4 f1 = *reinterpret_cast<const float4*>(&ft[ci * STR + trr + 4]);
      float4 w0 = *reinterpret_cast<const float4*>(&Wl[ci * WSTR + tcc]);
      float4 w1 = *reinterpret_cast<const float4*>(&Wl[ci * WSTR + tcc + 4]);
      float fv[8] = {f0.x, f0.y, f0.z, f0.w, f1.x, f1.y, f1.z, f1.w};
      float wv[8] = {w0.x, w0.y, w0.z, w0.w, w1.x, w1.y, w1.z, w1.w};
      #pragma unroll
      for (int a = 0; a < 8; ++a)
        #pragma unroll
        for (int b = 0; b < 8; ++b)
          acc[a][b] = fmaf(fv[a], wv[b], acc[a][b]);
    }
    __syncthreads();
  }

  // ---- reduce partial sums across split groups (tree via LDS) ----
  if constexpr (SPLIT > 1) {
    float* red = smem;
    for (int off = SPLIT / 2; off >= 1; off >>= 1) {
      __syncthreads();
      if (sp >= off && sp < 2 * off) {
        float* dst = red + ((size_t)((sp - off) * NSLOT + slot)) * 64;
        #pragma unroll
        for (int a = 0; a < 8; ++a) {
          float4 v0 = {acc[a][0], acc[a][1], acc[a][2], acc[a][3]};
          float4 v1 = {acc[a][4], acc[a][5], acc[a][6], acc[a][7]};
          *reinterpret_cast<float4*>(dst + a * 8)     = v0;
          *reinterpret_cast<float4*>(dst + a * 8 + 4) = v1;
        }
      }
      __syncthreads();
      if (sp < off) {
        const float* s = red + ((size_t)(sp * NSLOT + slot)) * 64;
        #pragma unroll
        for (int a = 0; a < 8; ++a) {
          float4 v0 = *reinterpret_cast<const float4*>(s + a * 8);
          float4 v1 = *reinterpret_cast<const float4*>(s + a * 8 + 4);
          acc[a][0] += v0.x; acc[a][1] += v0.y; acc[a][2] += v0.z; acc[a][3] += v0.w;
          acc[a][4] += v1.x; acc[a][5] += v1.y; acc[a][6] += v1.z; acc[a][7] += v1.w;
        }
      }
    }
  }

  // ---- epilogue ----
  if (sp == 0) {
    #pragma unroll
    for (int a = 0; a < 8; ++a) {
      int r = base + trr + a;
      float o[8];
      #pragma unroll
      for (int b = 0; b < 8; ++b) {
        float v = acc[a][b] + bias[tcc + b];
        if (RELU) v = v > 0.f ? v : 0.f;
        o[b] = v;
      }
      if (RESID) {
        const float* rs = resid + (size_t)r * 64 + coff + tcc;
        float4 r0 = *reinterpret_cast<const float4*>(rs);
        float4 r1 = *reinterpret_cast<const float4*>(rs + 4);
        o[0] += r0.x; o[1] += r0.y; o[2] += r0.z; o[3] += r0.w;
        o[4] += r1.x; o[5] += r1.y; o[6] += r1.z; o[7] += r1.w;
      }
      float* dst = outp + (size_t)r * ostride + coff + tcc;
      float4 s0 = {o[0], o[1], o[2], o[3]};
      float4 s1 = {o[4], o[5], o[6], o[7]};
      *reinterpret_cast<float4*>(dst)     = s0;
      *reinterpret_cast<float4*>(dst + 4) = s1;
    }
  }
}

// ---------------------------------------------------------------------------
// upsample: out[(n*8+k)*64 + c] = relu(x[n] @ Wup[k] + bup)
// ---------------------------------------------------------------------------
__global__ __launch_bounds__(256)
void upsample_kernel(const float* __restrict__ x, const float* __restrict__ Wup,
                     const float* __restrict__ bup, float* __restrict__ outp)
{
  __shared__ float Wl[64 * 64];
  __shared__ float xt[64][68];
  const int t    = threadIdx.x;
  const int tile = blockIdx.x >> 3;
  const int k    = blockIdx.x & 7;
  const int base = tile * 64;

  #pragma unroll
  for (int i = t; i < 4096; i += 256) Wl[i] = Wup[k * 4096 + i];
  {
    const int gr = t >> 2, gp = t & 3;
    const float4* src = reinterpret_cast<const float4*>(x + (size_t)(base + gr) * 64) + gp * 4;
    #pragma unroll
    for (int j = 0; j < 4; ++j) {
      float4 v = src[j];
      int ci = (gp * 4 + j) * 4;
      xt[ci + 0][gr] = v.x; xt[ci + 1][gr] = v.y;
      xt[ci + 2][gr] = v.z; xt[ci + 3][gr] = v.w;
    }
  }
  __syncthreads();
  const int tcc = (t % 16) * 4, trr = (t / 16) * 4;
  float acc[4][4];
  #pragma unroll
  for (int a = 0; a < 4; ++a)
    #pragma unroll
    for (int b = 0; b < 4; ++b) acc[a][b] = 0.f;
  #pragma unroll
  for (int ci = 0; ci < 64; ++ci) {
    float4 f = *reinterpret_cast<const float4*>(&xt[ci][trr]);
    float4 w = *reinterpret_cast<const float4*>(&Wl[ci * 64 + tcc]);
    float fv[4] = {f.x, f.y, f.z, f.w};
    float wv[4] = {w.x, w.y, w.z, w.w};
    #pragma unroll
    for (int a = 0; a < 4; ++a)
      #pragma unroll
      for (int b = 0; b < 4; ++b) acc[a][b] = fmaf(fv[a], wv[b], acc[a][b]);
  }
  #pragma unroll
  for (int a = 0; a < 4; ++a) {
    int n = base + trr + a;
    float4 o;
    float v0 = acc[a][0] + bup[tcc + 0]; o.x = v0 > 0.f ? v0 : 0.f;
    float v1 = acc[a][1] + bup[tcc + 1]; o.y = v1 > 0.f ? v1 : 0.f;
    float v2 = acc[a][2] + bup[tcc + 2]; o.z = v2 > 0.f ? v2 : 0.f;
    float v3 = acc[a][3] + bup[tcc + 3]; o.w = v3 > 0.f ? v3 : 0.f;
    *reinterpret_cast<float4*>(outp + ((size_t)n * 8 + k) * 64 + tcc) = o;
  }
}

// ---------------------------------------------------------------------------
// classifier conv
// ---------------------------------------------------------------------------
__global__ __launch_bounds__(256)
void cls_kernel(const float* __restrict__ feats, const int* __restrict__ nbr,
                const float* __restrict__ Wcls, const float* __restrict__ bcls,
                float* __restrict__ out_cls)
{
  const int wave = threadIdx.x >> 6;
  const int lane = threadIdx.x & 63;
  float wreg[27];
  #pragma unroll
  for (int k = 0; k < 27; ++k) wreg[k] = Wcls[k * 64 + lane];
  const int base = blockIdx.x * 32 + wave * 8;
  for (int rr = 0; rr < 8; ++rr) {
    const int n = base + rr;
    float s = 0.f;
    #pragma unroll
    for (int k = 0; k < 27; ++k) {
      int idx = nbr[(size_t)k * NOUTC + n];
      s = fmaf(feats[(size_t)idx * 64 + lane], wreg[k], s);
    }
    #pragma unroll
    for (int off = 32; off >= 1; off >>= 1) s += __shfl_xor(s, off, 64);
    if (lane == 0) out_cls[n] = s + bcls[0];
  }
}

// ---------------------------------------------------------------------------
// init / detect / top-k select / prune
// ---------------------------------------------------------------------------
__global__ void init_kernel(uint* hist1, uint* hist2, int* tie_cnt, int* flag,
                            float* fa, float* fb, float* t0, float* t1)
{
  int i = blockIdx.x * 256 + threadIdx.x;
  if (i < 65536) hist1[i] = 0;
  else if (i < 131072) hist2[i - 65536] = 0;
  if (i == 0) { tie_cnt[0] = 0; flag[0] = 0; }
  if (i < 64) { fa[(size_t)NOUTC * 64 + i] = 0.f; fb[(size_t)NOUTC * 64 + i] = 0.f; }
  if (i < 16) { t0[(size_t)NOUTC * 16 + i] = 0.f; t1[(size_t)NOUTC * 16 + i] = 0.f; }
}

__global__ void detect_kernel(const unsigned char* __restrict__ mt, int* flag)
{
  int i = blockIdx.x * 256 + threadIdx.x;
  int p = i * 4 + 1;
  if (p < NOUTC && mt[p] != 0) flag[0] = 1;
}

__global__ void hist1_kernel(const float* __restrict__ cls, uint* __restrict__ hist)
{
  for (int i = blockIdx.x * blockDim.x + threadIdx.x; i < NOUTC; i += gridDim.x * blockDim.x)
    atomicAdd(&hist[fkey(cls[i]) >> 16], 1u);
}

__global__ void scan1_kernel(const uint* __restrict__ hist, const int* __restrict__ nums,
                             uint* __restrict__ res)
{
  __shared__ uint chunk[256];
  const int t = threadIdx.x;
  uint s = 0;
  for (int j = 0; j < 256; ++j) s += hist[t * 256 + j];
  chunk[t] = s;
  __syncthreads();
  if (t == 0) {
    uint k = (uint)nums[0];
    uint cum = 0; int c = 255;
    for (; c > 0; --c) { if (cum + chunk[c] >= k) break; cum += chunk[c]; }
    int B = c * 256; uint cum2 = cum;
    for (int b = c * 256 + 255; b >= c * 256; --b) {
      if (cum2 + hist[b] >= k) { B = b; break; }
      cum2 += hist[b];
    }
    res[0] = (uint)B; res[1] = cum2;
  }
}

__global__ void hist2_kernel(const float* __restrict__ cls, const uint* __restrict__ res1,
                             uint* __restrict__ hist)
{
  const uint B = res1[0];
  for (int i = blockIdx.x * blockDim.x + threadIdx.x; i < NOUTC; i += gridDim.x * blockDim.x) {
    uint key = fkey(cls[i]);
    if ((key >> 16) == B) atomicAdd(&hist[key & 0xffffu], 1u);
  }
}

__global__ void scan2_kernel(const uint* __restrict__ hist, const uint* __restrict__ res1,
                             const int* __restrict__ nums, uint* __restrict__ res2)
{
  __shared__ uint chunk[256];
  const int t = threadIdx.x;
  uint s = 0;
  for (int j = 0; j < 256; ++j) s += hist[t * 256 + j];
  chunk[t] = s;
  __syncthreads();
  if (t == 0) {
    uint k = (uint)nums[0];
    uint cum = res1[1]; int c = 255;
    for (; c > 0; --c) { if (cum + chunk[c] >= k) break; cum += chunk[c]; }
    int L = c * 256; uint cum2 = cum;
    for (int b = c * 256 + 255; b >= c * 256; --b) {
      if (cum2 + hist[b] >= k) { L = b; break; }
      cum2 += hist[b];
    }
    res2[0] = (res1[0] << 16) | (uint)L;
    res2[1] = k - cum2;
  }
}

__global__ void mark_kernel(const float* __restrict__ cls, const uint* __restrict__ res2,
                            unsigned char* __restrict__ msel, int* tie_cnt, int* tie_idx)
{
  const uint T = res2[0];
  for (int i = blockIdx.x * blockDim.x + threadIdx.x; i < NOUTC; i += gridDim.x * blockDim.x) {
    uint key = fkey(cls[i]);
    msel[i] = key > T ? 1 : 0;
    if (key == T) {
      int p = atomicAdd(tie_cnt, 1);
      if (p < 4096) tie_idx[p] = i;
    }
  }
}

__global__ void tie_kernel(const uint* __restrict__ res2, const int* __restrict__ tie_cnt,
                           const int* __restrict__ tie_idx, unsigned char* __restrict__ msel)
{
  int need = (int)res2[1];
  int cnt = tie_cnt[0]; if (cnt > 4096) cnt = 4096;
  if (need <= 0) return;
  if (cnt <= need) {
    for (int i = threadIdx.x; i < cnt; i += 256) msel[tie_idx[i]] = 1;
  } else {
    for (int i = threadIdx.x; i < cnt; i += 256) {
      int my = tie_idx[i];
      int rank = 0;
      for (int j = 0; j < cnt; ++j) rank += (tie_idx[j] < my) ? 1 : 0;
      if (rank < need) msel[my] = 1;
    }
  }
}

__global__ void prune_kernel(const float* __restrict__ feats, const unsigned char* __restrict__ msel,
                             const void* __restrict__ mtrue, const int* __restrict__ flag,
                             float* __restrict__ dout)
{
  const unsigned char* mb = (const unsigned char*)mtrue;
  const int* mi = (const int*)mtrue;
  const bool bytes = (flag[0] != 0);
  float* pruned = dout + NOUTC;
  float* maskf  = dout + NOUTC + (size_t)NOUTC * 64;
  const float4* src = reinterpret_cast<const float4*>(feats);
  float4* dst = reinterpret_cast<float4*>(pruned);
  const int total = NOUTC * 16;
  for (int i = blockIdx.x * blockDim.x + threadIdx.x; i < total; i += gridDim.x * blockDim.x) {
    int n = i >> 4;
    bool mt = bytes ? (mb[n] != 0) : (mi[n] != 0);
    bool m = (msel[n] != 0) || mt;
    float4 v = src[i];
    float4 z = {0.f, 0.f, 0.f, 0.f};
    dst[i] = m ? v : z;
    if ((i & 15) == 0) maskf[n] = m ? 1.f : 0.f;
  }
}

// ---------------------------------------------------------------------------
extern "C" void kernel_launch(void* const* d_in, const int* in_sizes, int n_in,
                              void* d_out, int out_size, void* d_ws, size_t ws_size,
                              hipStream_t stream)
{
  const float* x    = (const float*)d_in[0];
  const float* Wup  = (const float*)d_in[1];
  const float* bup  = (const float*)d_in[2];
  const float* Wc0  = (const float*)d_in[3];
  const float* bc0  = (const float*)d_in[4];
  const float* W00  = (const float*)d_in[5];
  const float* b00  = (const float*)d_in[6];
  const float* W01  = (const float*)d_in[7];
  const float* b01  = (const float*)d_in[8];
  const float* W10  = (const float*)d_in[9];
  const float* b10  = (const float*)d_in[10];
  const float* W11  = (const float*)d_in[11];
  const float* b11  = (const float*)d_in[12];
  const float* W12  = (const float*)d_in[13];
  const float* b12  = (const float*)d_in[14];
  const float* Wcls = (const float*)d_in[15];
  const float* bcls = (const float*)d_in[16];
  const int*   nbr  = (const int*)d_in[17];
  const void*  mtrue= d_in[18];
  const int*   nums = (const int*)d_in[19];

  float* dout = (float*)d_out;

  float* fa = (float*)d_ws;
  float* t0 = fa + (size_t)(NOUTC + 1) * 64;
  float* t1 = t0 + (size_t)(NOUTC + 1) * 16;
  uint*  hist1 = (uint*)(t1 + (size_t)(NOUTC + 1) * 16);
  uint*  hist2 = hist1 + 65536;
  uint*  res1  = hist2 + 65536;
  uint*  res2  = res1 + 2;
  int*   tie_cnt = (int*)(res2 + 2);
  int*   flag    = tie_cnt + 1;
  int*   tie_idx = flag + 1;
  unsigned char* msel = (unsigned char*)(tie_idx + 4096);
  float* fb = dout + NOUTC;   // (N+1)*64 parked in d_out's pruned+mask region

  init_kernel<<<512, 256, 0, stream>>>(hist1, hist2, tie_cnt, flag, fa, fb, t0, t1);
  detect_kernel<<<128, 256, 0, stream>>>((const unsigned char*)mtrue, flag);

  upsample_kernel<<<2048, 256, 0, stream>>>(x, Wup, bup, fa);

  // c0: 64->64, 27 taps
  spconv2<128, 64, 64, 2, 256, 27, false, true, false>
      <<<NOUTC / 128, 256, 0, stream>>>(fa, nbr, Wc0, bc0, nullptr, fb, 64, 0);

  const float* cur = fb; float* nxt = fa;
  for (int i = 0; i < 3; ++i) {
    // t0 = relu(spconv(cur, W00))   64->16, 27 taps
    spconv2<128, 64, 16, 4, 128, 27, false, true, false>
        <<<NOUTC / 128, 128, 0, stream>>>(cur, nbr, W00 + (size_t)i * 27 * 64 * 16,
                                          b00 + i * 16, nullptr, t0, 16, 0);
    // nxt[:,0:32] = spconv(t0, W01) + b01 + cur[:,0:32]   16->32, 27 taps
    spconv2<128, 16, 32, 4, 256, 27, false, false, true>
        <<<NOUTC / 128, 256, 0, stream>>>(t0, nbr, W01 + (size_t)i * 27 * 16 * 32,
                                          b01 + i * 32, cur, nxt, 64, 0);
    // t1 = relu(cur @ W10 + b10)    64->16, 1x1
    spconv2<128, 64, 16, 4, 128, 1, true, true, false>
        <<<NOUTC / 128, 128, 0, stream>>>(cur, nullptr, W10 + (size_t)i * 64 * 16,
                                          b10 + i * 16, nullptr, t1, 16, 0);
    // t0 = relu(spconv(t1, W11))    16->16, 27 taps
    spconv2<128, 16, 16, 4, 128, 27, false, true, false>
        <<<NOUTC / 128, 128, 0, stream>>>(t1, nbr, W11 + (size_t)i * 27 * 16 * 16,
                                          b11 + i * 16, nullptr, t0, 16, 0);
    // nxt[:,32:64] = t0 @ W12 + b12 + cur[:,32:64]   16->32, 1x1
    spconv2<128, 16, 32, 4, 256, 1, true, false, true>
        <<<NOUTC / 128, 256, 0, stream>>>(t0, nullptr, W12 + (size_t)i * 16 * 32,
                                          b12 + i * 32, cur, nxt, 64, 32);
    float* tmp = (float*)cur; cur = nxt; nxt = tmp;
  }
  // final features in fa

  cls_kernel<<<NOUTC / 32, 256, 0, stream>>>(cur, nbr, Wcls, bcls, dout);

  hist1_kernel<<<512, 256, 0, stream>>>(dout, hist1);
  scan1_kernel<<<1, 256, 0, stream>>>(hist1, nums, res1);
  hist2_kernel<<<512, 256, 0, stream>>>(dout, res1, hist2);
  scan2_kernel<<<1, 256, 0, stream>>>(hist2, res1, nums, res2);
  mark_kernel<<<512, 256, 0, stream>>>(dout, res2, msel, tie_cnt, tie_idx);
  tie_kernel<<<1, 256, 0, stream>>>(res2, tie_cnt, tie_idx, msel);
  prune_kernel<<<4096, 256, 0, stream>>>(cur, msel, mtrue, flag, dout);
}